// Round 4
// baseline (318.735 us; speedup 1.0000x reference)
//
#include <hip/hip_runtime.h>
#include <hip/hip_bf16.h>
#include <stdint.h>

// Problem constants (fixed by the reference)
#define NTOK 4096
#define HID  512
#define INSZ 1024   // E + H
#define KIN  1536   // INSZ + HID (fused LSTM input: x | h)
#define KCAT 64
#define CCH  128
#define MCELL 4
#define G4H  2048   // 4*H

typedef unsigned short u16;
typedef __bf16 bf16x8 __attribute__((ext_vector_type(8)));
typedef float  f32x4  __attribute__((ext_vector_type(4)));

__device__ __forceinline__ u16 f2bf(float f) {
    unsigned u = __float_as_uint(f);
    u += 0x7fffu + ((u >> 16) & 1u);   // RTNE
    return (u16)(u >> 16);
}
__device__ __forceinline__ void store_bf4(u16* p, float4 v) {
    ushort4 r;
    r.x = f2bf(v.x); r.y = f2bf(v.y); r.z = f2bf(v.z); r.w = f2bf(v.w);
    *reinterpret_cast<ushort4*>(p) = r;
}
__device__ __forceinline__ void gl16(const u16* g, u16* l) {
    __builtin_amdgcn_global_load_lds((const __attribute__((address_space(1))) void*)g,
                                     (__attribute__((address_space(3))) void*)l, 16, 0, 0);
}

// pack_all grid segmentation
#define PK_A   4096                 // A rows (token order)
#define PK_W   8192                 // Wb rows
#define PK_L   2731                 // Wlin: 3x512 rows/block (8192 rows)
#define PK_E   1366                 // et:   3x512 rows/block (4096 rows)
#define PK_TOT (PK_A + PK_W + PK_L + PK_E + 1)

// meta layout (ints): [0..3] ci padded cnt, [4..7] ci padded off,
//                     [8..71] cat padded cnt, [72..135] cat padded off
// ---------------------------------------------------------------------------
// Kernel 1: fused pack (A tok-order, Wb, Wlin, et_b -> bf16) + build_perm
// (last block). perm consumers are all in the next dispatch -> no sync needed.
// ---------------------------------------------------------------------------
__global__ __launch_bounds__(192) void pack_all(
    const float* __restrict__ x, const float* __restrict__ h,
    const float* __restrict__ Wih, const float* __restrict__ Whh,
    const float* __restrict__ W_lin, const float* __restrict__ et,
    const int* __restrict__ ci, const int* __restrict__ cat,
    u16* __restrict__ A_pack, u16* __restrict__ Wb, u16* __restrict__ Wlin,
    u16* __restrict__ et_b,
    int* __restrict__ meta, int* __restrict__ perm_ci, int* __restrict__ perm_cat)
{
    int b = blockIdx.x;
    int tid = threadIdx.x;
    int c = tid * 8;
    if (b < PK_A) {                       // A row, token order
        const float* src = (c < INSZ) ? (x + (size_t)b * INSZ + c)
                                      : (h + (size_t)b * HID + (c - INSZ));
        u16* dst = A_pack + (size_t)b * KIN + c;
        store_bf4(dst, *(const float4*)src);
        store_bf4(dst + 4, *(const float4*)(src + 4));
    } else if (b < PK_A + PK_W) {         // Wb row (m*2048+j), natural order
        int row = b - PK_A;
        int m = row >> 11, j = row & 2047;
        const float* src = (c < INSZ) ? (Wih + ((size_t)m * G4H + j) * INSZ + c)
                                      : (Whh + ((size_t)m * G4H + j) * HID + (c - INSZ));
        u16* dst = Wb + (size_t)row * KIN + c;
        store_bf4(dst, *(const float4*)src);
        store_bf4(dst + 4, *(const float4*)(src + 4));
    } else if (b < PK_A + PK_W + PK_L) {  // Wlin: 3 rows of 512 per block
        int row = (b - (PK_A + PK_W)) * 3 + (c >> 9);
        int col = c & 511;
        if (row >= KCAT * CCH) return;
        const float* src = W_lin + (size_t)row * HID + col;
        u16* dst = Wlin + (size_t)row * HID + col;
        store_bf4(dst, *(const float4*)src);
        store_bf4(dst + 4, *(const float4*)(src + 4));
    } else if (b < PK_A + PK_W + PK_L + PK_E) {   // et: 3 rows of 512 per block
        int row = (b - (PK_A + PK_W + PK_L)) * 3 + (c >> 9);
        int col = c & 511;
        if (row >= NTOK) return;
        const float* src = et + (size_t)row * HID + col;
        u16* dst = et_b + (size_t)row * HID + col;
        store_bf4(dst, *(const float4*)src);
        store_bf4(dst + 4, *(const float4*)(src + 4));
    } else {                              // build_perm (single block, 192 thr)
        __shared__ int cnt_ci[MCELL], cur_ci[MCELL];
        __shared__ int cnt_cat[KCAT], cur_cat[KCAT];
        if (tid < MCELL) cnt_ci[tid] = 0;
        if (tid < KCAT)  cnt_cat[tid] = 0;
        __syncthreads();
        for (int t = tid; t < NTOK; t += 192) {
            atomicAdd(&cnt_ci[ci[t]], 1);
            atomicAdd(&cnt_cat[cat[t]], 1);
        }
        __syncthreads();
        if (tid == 0) {
            int off = 0;
            for (int m = 0; m < MCELL; ++m) {
                int p = (cnt_ci[m] + 127) & ~127;
                meta[m] = p; meta[4 + m] = off; cur_ci[m] = off; off += p;
            }
            off = 0;
            for (int k = 0; k < KCAT; ++k) {
                int p = (cnt_cat[k] + 63) & ~63;
                meta[8 + k] = p; meta[72 + k] = off; cur_cat[k] = off; off += p;
            }
        }
        __syncthreads();
        for (int i = tid; i < 4608; i += 192) perm_ci[i] = -1;
        for (int i = tid; i < 8192; i += 192) perm_cat[i] = -1;
        __syncthreads();
        for (int t = tid; t < NTOK; t += 192) {
            int s = atomicAdd(&cur_ci[ci[t]], 1);
            perm_ci[s] = t;
            int sc = atomicAdd(&cur_cat[cat[t]], 1);
            perm_cat[sc] = t;
        }
    }
}

// ---------------------------------------------------------------------------
// Kernel 2: fused GEMMs + LSTM pointwise.
//  z<4 : gates GEMM 128x128 (BK=32, 4x gl16/wave), gate-INTERLEAVED columns:
//        block ct covers weight rows {q*512 + ct*32 + j}, q=0..3(i,f,g,o),
//        j=0..31 -> after K-loop the block holds all 4 gates for 128 tokens
//        x 32 hidden. Transpose acc via LDS (stride 132 -> 2-way = free),
//        apply LSTM pointwise, write h2/c2 directly. No gates buffer.
//  z in {4,5}: log_odds GEMM 64x128, K=512, A gathered from et_b via gl16.
// ---------------------------------------------------------------------------
__global__ __launch_bounds__(256, 2) void mega_gemm(
    const u16* __restrict__ A_pack,   // [4096][1536] token order
    const u16* __restrict__ Wb,       // [4][2048][1536]
    const u16* __restrict__ Wlin,     // [64][128][512]
    const u16* __restrict__ et_b,     // [4096][512]
    const float* __restrict__ cin,    // [N,512] f32
    const float* __restrict__ b_ih,   // [4,2048]
    const float* __restrict__ b_hh,   // [4,2048]
    const float* __restrict__ b_lin,  // [64,128]
    const int* __restrict__ meta,
    const int* __restrict__ perm_ci,
    const int* __restrict__ perm_cat,
    float* __restrict__ out)          // [log_odds | h2 | c2]
{
    __shared__ __align__(16) unsigned char smem[33792];  // As|Bs overlay Cst
    __shared__ int   sperm[128];
    __shared__ float sbias[128];
    u16*   As  = (u16*)smem;            // 4096 u16 [0, 8192)
    u16*   Bs  = (u16*)(smem + 8192);   // 4096 u16 [8192, 16384)
    float* Cst = (float*)smem;          // 64 x 132 f32 = 33792 B (after K-loop)

    int tid = threadIdx.x;
    int lane = tid & 63, wave = tid >> 6;
    int r0 = tid >> 2, cb = tid & 3;            // staging row / 16B chunk
    int kcb = cb ^ ((r0 >> 1) & 3);             // source k-chunk (swizzle)
    int qd = lane >> 4, l15 = lane & 15;
    int qs = (qd ^ ((l15 >> 1) & 3)) * 8;       // frag-read k-chunk (u16)

    const size_t o_h2 = (size_t)NTOK * CCH;
    const size_t o_c2 = o_h2 + (size_t)NTOK * HID;

    if (blockIdx.z < 4) {
        // ---------------- gates GEMM + LSTM pointwise ----------------
        int m = blockIdx.z, rt = blockIdx.x, ct = blockIdx.y;   // ct: hh-tile
        int pcnt = meta[m];
        if (rt * 128 >= pcnt) return;
        int sbase = meta[4 + m] + rt * 128;

        if (tid < 128) {
            sperm[tid] = perm_ci[sbase + tid];
            int q = tid >> 5, j = tid & 31;
            int g = q * 512 + ct * 32 + j;
            sbias[tid] = b_ih[m * G4H + g] + b_hh[m * G4H + g];
        }
        __syncthreads();

        // A: gather rows via per-lane source addresses (token order A_pack)
        int tA0 = sperm[r0];      int fA0 = tA0 >= 0 ? tA0 : 0;
        int tA1 = sperm[64 + r0]; int fA1 = tA1 >= 0 ? tA1 : 0;
        const u16* gA0 = A_pack + (size_t)fA0 * KIN + kcb * 8;
        const u16* gA1 = A_pack + (size_t)fA1 * KIN + kcb * 8;
        // B: interleaved gate rows
        int q0 = r0 >> 5, j0 = r0 & 31;
        int brow0 = q0 * 512 + ct * 32 + j0;
        int brow1 = (q0 + 2) * 512 + ct * 32 + j0;
        const u16* gB0 = Wb + ((size_t)m * G4H + brow0) * KIN + kcb * 8;
        const u16* gB1 = Wb + ((size_t)m * G4H + brow1) * KIN + kcb * 8;
        u16* lA0 = As + wave * 512;
        u16* lA1 = As + 2048 + wave * 512;
        u16* lB0 = Bs + wave * 512;
        u16* lB1 = Bs + 2048 + wave * 512;

        int wr = wave >> 1, wc = wave & 1;

        f32x4 acc[4][4];
        #pragma unroll
        for (int i = 0; i < 4; ++i)
            #pragma unroll
            for (int j = 0; j < 4; ++j)
                acc[i][j] = (f32x4){0.f, 0.f, 0.f, 0.f};

        for (int ks = 0; ks < KIN / 32; ++ks) {
            gl16(gA0, lA0); gl16(gA1, lA1);
            gl16(gB0, lB0); gl16(gB1, lB1);
            gA0 += 32; gA1 += 32; gB0 += 32; gB1 += 32;
            __syncthreads();
            bf16x8 fa[4], fb[4];
            #pragma unroll
            for (int ti = 0; ti < 4; ++ti)
                fa[ti] = *reinterpret_cast<const bf16x8*>(&As[(wr * 64 + ti * 16 + l15) * 32 + qs]);
            #pragma unroll
            for (int tj = 0; tj < 4; ++tj)
                fb[tj] = *reinterpret_cast<const bf16x8*>(&Bs[(wc * 64 + tj * 16 + l15) * 32 + qs]);
            #pragma unroll
            for (int ti = 0; ti < 4; ++ti)
                #pragma unroll
                for (int tj = 0; tj < 4; ++tj)
                    acc[ti][tj] = __builtin_amdgcn_mfma_f32_16x16x32_bf16(fa[ti], fb[tj], acc[ti][tj], 0, 0, 0);
            __syncthreads();
        }

        // Two rounds: stage 64 rows of C to LDS, pointwise, store h2/c2.
        int hh = tid & 31;
        int rr = tid >> 5;                      // 0..7
        #pragma unroll
        for (int p = 0; p < 2; ++p) {
            if (wr == p) {
                #pragma unroll
                for (int ti = 0; ti < 4; ++ti)
                    #pragma unroll
                    for (int tj = 0; tj < 4; ++tj)
                        #pragma unroll
                        for (int r = 0; r < 4; ++r)
                            Cst[(ti * 16 + qd * 4 + r) * 132 + wc * 64 + tj * 16 + l15] = acc[ti][tj][r];
            }
            __syncthreads();
            #pragma unroll
            for (int it = 0; it < 8; ++it) {
                int lr = it * 8 + rr;           // 0..63
                int t = sperm[p * 64 + lr];
                if (t >= 0) {
                    float gi = Cst[lr * 132 +       hh] + sbias[hh];
                    float gf = Cst[lr * 132 +  32 + hh] + sbias[32 + hh];
                    float gg = Cst[lr * 132 +  64 + hh] + sbias[64 + hh];
                    float go = Cst[lr * 132 +  96 + hh] + sbias[96 + hh];
                    float si = 1.f / (1.f + __expf(-gi));
                    float sf = 1.f / (1.f + __expf(-gf));
                    float so = 1.f / (1.f + __expf(-go));
                    float cv = cin[(size_t)t * HID + ct * 32 + hh];
                    float c2 = sf * cv + si * tanhf(gg);
                    float h2 = so * tanhf(c2);
                    out[o_h2 + (size_t)t * HID + ct * 32 + hh] = h2;
                    out[o_c2 + (size_t)t * HID + ct * 32 + hh] = c2;
                }
            }
            __syncthreads();
        }
    } else {
        // ---------------- log_odds GEMM ----------------
        int id = (blockIdx.z - 4) * 512 + blockIdx.y * 32 + blockIdx.x; // [0,1024)
        int k = id & 63, rtl = id >> 6;
        int pcnt = meta[8 + k];
        if (rtl * 64 >= pcnt) return;
        int base = meta[72 + k] + rtl * 64;

        if (tid < 64) sperm[tid] = perm_cat[base + tid];
        __syncthreads();

        // B = Wlin[k] 128x512 via gl16 into As region
        const u16* gW0 = Wlin + ((size_t)k * CCH + r0) * HID + kcb * 8;
        const u16* gW1 = gW0 + (size_t)64 * HID;
        u16* lW0 = As + wave * 512;
        u16* lW1 = As + 2048 + wave * 512;
        // A = et rows gathered via per-lane gl16 into Bs region (64x32)
        int ta = sperm[r0 & 63]; int fa_t = ta >= 0 ? ta : 0;
        const u16* gE = et_b + (size_t)fa_t * HID + kcb * 8;
        u16* lE = Bs + wave * 512;

        f32x4 acc[4][2];
        #pragma unroll
        for (int i = 0; i < 4; ++i) {
            acc[i][0] = (f32x4){0.f, 0.f, 0.f, 0.f};
            acc[i][1] = (f32x4){0.f, 0.f, 0.f, 0.f};
        }

        for (int kk = 0; kk < HID; kk += 32) {
            gl16(gW0, lW0); gl16(gW1, lW1); gl16(gE, lE);
            gW0 += 32; gW1 += 32; gE += 32;
            __syncthreads();
            bf16x8 fa[4], fb[2];
            #pragma unroll
            for (int ti = 0; ti < 4; ++ti)
                fa[ti] = *reinterpret_cast<const bf16x8*>(&Bs[(ti * 16 + l15) * 32 + qs]);
            #pragma unroll
            for (int tj = 0; tj < 2; ++tj)
                fb[tj] = *reinterpret_cast<const bf16x8*>(&As[(wave * 32 + tj * 16 + l15) * 32 + qs]);
            #pragma unroll
            for (int ti = 0; ti < 4; ++ti)
                #pragma unroll
                for (int tj = 0; tj < 2; ++tj)
                    acc[ti][tj] = __builtin_amdgcn_mfma_f32_16x16x32_bf16(fa[ti], fb[tj], acc[ti][tj], 0, 0, 0);
            __syncthreads();
        }

        #pragma unroll
        for (int ti = 0; ti < 4; ++ti) {
            #pragma unroll
            for (int tj = 0; tj < 2; ++tj) {
                int n = wave * 32 + tj * 16 + l15;
                #pragma unroll
                for (int r = 0; r < 4; ++r) {
                    int row = ti * 16 + qd * 4 + r;
                    int t = sperm[row];
                    if (t >= 0)
                        out[(size_t)t * CCH + n] = acc[ti][tj][r] + b_lin[k * CCH + n];
                }
            }
        }
    }
}

// ---------------------------------------------------------------------------
extern "C" void kernel_launch(void* const* d_in, const int* in_sizes, int n_in,
                              void* d_out, int out_size, void* d_ws, size_t ws_size,
                              hipStream_t stream) {
    const float* et    = (const float*)d_in[0];
    const float* x     = (const float*)d_in[1];
    const float* h     = (const float*)d_in[2];
    const float* c     = (const float*)d_in[3];
    const int*   cat   = (const int*)d_in[4];
    const int*   ci    = (const int*)d_in[5];
    const float* W_lin = (const float*)d_in[6];
    const float* b_lin = (const float*)d_in[7];
    const float* W_ih  = (const float*)d_in[8];
    const float* W_hh  = (const float*)d_in[9];
    const float* b_ih  = (const float*)d_in[10];
    const float* b_hh  = (const float*)d_in[11];
    float* out = (float*)d_out;

    char* ws = (char*)d_ws;
    int* meta     = (int*)ws;                         // 136 ints
    int* perm_ci  = (int*)(ws + 1024);                // 4608 ints -> ends 19456
    int* perm_cat = (int*)(ws + 19456);               // 8192 ints -> ends 52224
    u16* A_pack   = (u16*)(ws + 65536);               // 4096*1536*2 = 12582912
    u16* Wb       = (u16*)(ws + 65536 + 12582912);    // 8192*1536*2 = 25165824
    u16* Wlin     = (u16*)(ws + 65536 + 12582912 + 25165824);            // 8388608
    u16* et_b     = (u16*)(ws + 65536 + 12582912 + 25165824 + 8388608);  // 4194304
    // total ws use ~50.4 MB

    pack_all<<<PK_TOT, 192, 0, stream>>>(x, h, W_ih, W_hh, W_lin, et, ci, cat,
                                         A_pack, Wb, Wlin, et_b,
                                         meta, perm_ci, perm_cat);

    dim3 ggrid(32, 16, 6);   // z<4: gates (rt,ct); z in {4,5}: logodds tiles
    mega_gemm<<<ggrid, 256, 0, stream>>>(A_pack, Wb, Wlin, et_b, c,
                                         b_ih, b_hh, b_lin, meta,
                                         perm_ci, perm_cat, out);
}

// Round 5
// 287.580 us; speedup vs baseline: 1.1083x; 1.1083x over previous
//
#include <hip/hip_runtime.h>
#include <hip/hip_bf16.h>
#include <stdint.h>

// Problem constants (fixed by the reference)
#define NTOK 4096
#define HID  512
#define INSZ 1024   // E + H
#define KIN  1536   // INSZ + HID (fused LSTM input: x | h)
#define KCAT 64
#define CCH  128
#define MCELL 4
#define G4H  2048   // 4*H

typedef unsigned short u16;
typedef __bf16 bf16x8 __attribute__((ext_vector_type(8)));
typedef float  f32x4  __attribute__((ext_vector_type(4)));

__device__ __forceinline__ u16 f2bf(float f) {
    unsigned u = __float_as_uint(f);
    u += 0x7fffu + ((u >> 16) & 1u);   // RTNE
    return (u16)(u >> 16);
}
__device__ __forceinline__ float bf2f(u16 v) {
    return __uint_as_float(((unsigned)v) << 16);
}
__device__ __forceinline__ void store_bf4(u16* p, float4 v) {
    ushort4 r;
    r.x = f2bf(v.x); r.y = f2bf(v.y); r.z = f2bf(v.z); r.w = f2bf(v.w);
    *reinterpret_cast<ushort4*>(p) = r;
}
__device__ __forceinline__ void gl16(const u16* g, u16* l) {
    __builtin_amdgcn_global_load_lds((const __attribute__((address_space(1))) void*)g,
                                     (__attribute__((address_space(3))) void*)l, 16, 0, 0);
}

// meta layout (ints): [0..3] ci padded cnt, [4..7] ci padded off,
//                     [8..71] cat padded cnt, [72..135] cat padded off
// ---------------------------------------------------------------------------
// Dispatch 0: pack Wb (W_ih|W_hh -> bf16) + Wlin (bf16) + build_perm (last blk)
// ---------------------------------------------------------------------------
#define P0_W 8192
#define P0_L 2731
__global__ __launch_bounds__(192) void pack_all(
    const float* __restrict__ Wih, const float* __restrict__ Whh,
    const float* __restrict__ W_lin,
    const int* __restrict__ ci, const int* __restrict__ cat,
    u16* __restrict__ Wb, u16* __restrict__ Wlin,
    int* __restrict__ meta, int* __restrict__ perm_ci, int* __restrict__ perm_cat)
{
    int b = blockIdx.x;
    int tid = threadIdx.x;
    int c = tid * 8;
    if (b < P0_W) {                       // Wb row (m*2048+j)
        int m = b >> 11, j = b & 2047;
        const float* src = (c < INSZ) ? (Wih + ((size_t)m * G4H + j) * INSZ + c)
                                      : (Whh + ((size_t)m * G4H + j) * HID + (c - INSZ));
        u16* dst = Wb + (size_t)b * KIN + c;
        store_bf4(dst, *(const float4*)src);
        store_bf4(dst + 4, *(const float4*)(src + 4));
    } else if (b < P0_W + P0_L) {         // Wlin: 3 rows of 512 per block
        int row = (b - P0_W) * 3 + (c >> 9);
        int col = c & 511;
        if (row >= KCAT * CCH) return;
        const float* src = W_lin + (size_t)row * HID + col;
        u16* dst = Wlin + (size_t)row * HID + col;
        store_bf4(dst, *(const float4*)src);
        store_bf4(dst + 4, *(const float4*)(src + 4));
    } else {                              // build_perm (single block)
        __shared__ int cnt_ci[MCELL], cur_ci[MCELL];
        __shared__ int cnt_cat[KCAT], cur_cat[KCAT];
        if (tid < MCELL) cnt_ci[tid] = 0;
        if (tid < KCAT)  cnt_cat[tid] = 0;
        __syncthreads();
        for (int t = tid; t < NTOK; t += 192) {
            atomicAdd(&cnt_ci[ci[t]], 1);
            atomicAdd(&cnt_cat[cat[t]], 1);
        }
        __syncthreads();
        if (tid == 0) {
            int off = 0;
            for (int m = 0; m < MCELL; ++m) {
                int p = (cnt_ci[m] + 127) & ~127;
                meta[m] = p; meta[4 + m] = off; cur_ci[m] = off; off += p;
            }
            off = 0;
            for (int k = 0; k < KCAT; ++k) {
                int p = (cnt_cat[k] + 63) & ~63;
                meta[8 + k] = p; meta[72 + k] = off; cur_cat[k] = off; off += p;
            }
        }
        __syncthreads();
        for (int i = tid; i < 4608; i += 192) perm_ci[i] = -1;
        for (int i = tid; i < 8192; i += 192) perm_cat[i] = -1;
        __syncthreads();
        for (int t = tid; t < NTOK; t += 192) {
            int s = atomicAdd(&cur_ci[ci[t]], 1);
            perm_ci[s] = t;
            int sc = atomicAdd(&cur_cat[cat[t]], 1);
            perm_cat[sc] = t;
        }
    }
}

// ---------------------------------------------------------------------------
// Dispatch 1: slot-ordered packs (need perm): A_pack (ci-slot order, also
// builds inv_ci) and et_s (cat-slot order).
// ---------------------------------------------------------------------------
#define P1_A 4608
#define P1_E 2731
__global__ __launch_bounds__(192) void pack_slots(
    const float* __restrict__ x, const float* __restrict__ h,
    const float* __restrict__ et,
    const int* __restrict__ perm_ci, const int* __restrict__ perm_cat,
    u16* __restrict__ A_pack, u16* __restrict__ et_s, int* __restrict__ inv_ci)
{
    int b = blockIdx.x;
    int tid = threadIdx.x;
    int c = tid * 8;
    if (b < P1_A) {                       // A row, ci-slot order
        int t = perm_ci[b];
        if (tid == 0 && t >= 0) inv_ci[t] = b;
        u16* dst = A_pack + (size_t)b * KIN + c;
        if (t < 0) {
            *reinterpret_cast<int4*>(dst) = make_int4(0, 0, 0, 0);
            return;
        }
        const float* src = (c < INSZ) ? (x + (size_t)t * INSZ + c)
                                      : (h + (size_t)t * HID + (c - INSZ));
        store_bf4(dst, *(const float4*)src);
        store_bf4(dst + 4, *(const float4*)(src + 4));
    } else {                              // et_s: 3 rows of 512 per block
        int row = (b - P1_A) * 3 + (c >> 9);
        int col = c & 511;
        if (row >= 8192) return;
        int t = perm_cat[row];
        u16* dst = et_s + (size_t)row * HID + col;
        if (t < 0) {
            *reinterpret_cast<int4*>(dst) = make_int4(0, 0, 0, 0);
            return;
        }
        const float* src = et + (size_t)t * HID + col;
        store_bf4(dst, *(const float4*)src);
        store_bf4(dst + 4, *(const float4*)(src + 4));
    }
}

// ---------------------------------------------------------------------------
// Dispatch 2: fused GEMMs, BK=64 (half the barrier drains of BK=32).
//  z<4 : gates GEMM 128x128, K=1536 (24 iters), slot-ordered A, bf16 gates out.
//  z in {4,5}: log_odds GEMM 64x128, K=512 (8 iters), slot-ordered et_s.
// LDS layout: row r holds 8 chunks of 8 u16; chunk cc stores global k-chunk
// cc ^ (r&7)  -> ds_read_b128 lands 2-way bank aliasing (free).
// ---------------------------------------------------------------------------
__global__ __launch_bounds__(256, 2) void mega_gemm(
    const u16* __restrict__ A_pack,   // [4608][1536] ci-slot order
    const u16* __restrict__ Wb,       // [4][2048][1536]
    const u16* __restrict__ Wlin,     // [64][128][512]
    const u16* __restrict__ et_s,     // [8192][512] cat-slot order
    const float* __restrict__ b_lin,  // [64,128]
    const int* __restrict__ meta,
    const int* __restrict__ perm_cat,
    u16* __restrict__ gates,          // [4608][2048] bf16, slot order
    float* __restrict__ out)          // log_odds at out[0..N*128)
{
    __shared__ __align__(16) u16 As[8192];   // 16 KB
    __shared__ __align__(16) u16 Bs[8192];   // 16 KB
    __shared__ int sperm[64];

    int tid = threadIdx.x;
    int lane = tid & 63, wave = tid >> 6;
    int rb = tid >> 3;                        // staging row-within-32 (0..31)
    int kc = (tid & 7) ^ (rb & 7);            // swizzled source k-chunk
    int qd = lane >> 4, l15 = lane & 15;
    int rsw = l15 & 7;                        // frag-read row swizzle key

    if (blockIdx.z < 4) {
        // ---------------- gates GEMM ----------------
        int m = blockIdx.z, rt = blockIdx.x, ct = blockIdx.y;
        int pcnt = meta[m];
        if (rt * 128 >= pcnt) return;
        int row0 = meta[4 + m] + rt * 128;

        const u16* gA[4]; const u16* gB[4];
        u16* lA[4]; u16* lB[4];
        #pragma unroll
        for (int i = 0; i < 4; ++i) {
            gA[i] = A_pack + (size_t)(row0 + i * 32 + rb) * KIN + kc * 8;
            gB[i] = Wb + ((size_t)m * G4H + ct * 128 + i * 32 + rb) * KIN + kc * 8;
            lA[i] = As + (i * 256 + wave * 64) * 8;
            lB[i] = Bs + (i * 256 + wave * 64) * 8;
        }

        int wr = wave >> 1, wc = wave & 1;

        f32x4 acc[4][4];
        #pragma unroll
        for (int i = 0; i < 4; ++i)
            #pragma unroll
            for (int j = 0; j < 4; ++j)
                acc[i][j] = (f32x4){0.f, 0.f, 0.f, 0.f};

        for (int ks = 0; ks < KIN / 64; ++ks) {
            #pragma unroll
            for (int i = 0; i < 4; ++i) { gl16(gA[i], lA[i]); gl16(gB[i], lB[i]); }
            #pragma unroll
            for (int i = 0; i < 4; ++i) { gA[i] += 64; gB[i] += 64; }
            __syncthreads();
            #pragma unroll
            for (int ks2 = 0; ks2 < 2; ++ks2) {
                bf16x8 fa[4], fb[4];
                #pragma unroll
                for (int ti = 0; ti < 4; ++ti) {
                    int row = wr * 64 + ti * 16 + l15;
                    int ch = (ks2 * 4 + qd) ^ rsw;
                    fa[ti] = *reinterpret_cast<const bf16x8*>(&As[row * 64 + ch * 8]);
                }
                #pragma unroll
                for (int tj = 0; tj < 4; ++tj) {
                    int row = wc * 64 + tj * 16 + l15;
                    int ch = (ks2 * 4 + qd) ^ rsw;
                    fb[tj] = *reinterpret_cast<const bf16x8*>(&Bs[row * 64 + ch * 8]);
                }
                #pragma unroll
                for (int ti = 0; ti < 4; ++ti)
                    #pragma unroll
                    for (int tj = 0; tj < 4; ++tj)
                        acc[ti][tj] = __builtin_amdgcn_mfma_f32_16x16x32_bf16(fa[ti], fb[tj], acc[ti][tj], 0, 0, 0);
            }
            __syncthreads();
        }

        #pragma unroll
        for (int ti = 0; ti < 4; ++ti) {
            #pragma unroll
            for (int tj = 0; tj < 4; ++tj) {
                int gcol = ct * 128 + wc * 64 + tj * 16 + l15;
                #pragma unroll
                for (int r = 0; r < 4; ++r) {
                    int grow = row0 + wr * 64 + ti * 16 + qd * 4 + r;
                    gates[(size_t)grow * G4H + gcol] = f2bf(acc[ti][tj][r]);
                }
            }
        }
    } else {
        // ---------------- log_odds GEMM ----------------
        int id = (blockIdx.z - 4) * 512 + blockIdx.y * 32 + blockIdx.x; // [0,1024)
        int k = id & 63, rtl = id >> 6;
        int pcnt = meta[8 + k];
        if (rtl * 64 >= pcnt) return;
        int base = meta[72 + k] + rtl * 64;

        if (tid < 64) sperm[tid] = perm_cat[base + tid];
        __syncthreads();

        // B = Wlin[k] (128 x 64 per iter) in As; A = et_s slots (64 x 64) in Bs
        const u16* gW[4]; u16* lW[4];
        #pragma unroll
        for (int i = 0; i < 4; ++i) {
            gW[i] = Wlin + ((size_t)k * CCH + i * 32 + rb) * HID + kc * 8;
            lW[i] = As + (i * 256 + wave * 64) * 8;
        }
        const u16* gE[2]; u16* lE[2];
        #pragma unroll
        for (int i = 0; i < 2; ++i) {
            gE[i] = et_s + (size_t)(base + i * 32 + rb) * HID + kc * 8;
            lE[i] = Bs + (i * 256 + wave * 64) * 8;
        }

        f32x4 acc[4][2];
        #pragma unroll
        for (int i = 0; i < 4; ++i) {
            acc[i][0] = (f32x4){0.f, 0.f, 0.f, 0.f};
            acc[i][1] = (f32x4){0.f, 0.f, 0.f, 0.f};
        }

        for (int kk = 0; kk < HID / 64; ++kk) {
            #pragma unroll
            for (int i = 0; i < 4; ++i) { gl16(gW[i], lW[i]); gW[i] += 64; }
            #pragma unroll
            for (int i = 0; i < 2; ++i) { gl16(gE[i], lE[i]); gE[i] += 64; }
            __syncthreads();
            #pragma unroll
            for (int ks2 = 0; ks2 < 2; ++ks2) {
                bf16x8 fa[4], fb[2];
                #pragma unroll
                for (int ti = 0; ti < 4; ++ti) {
                    int row = ti * 16 + l15;
                    int ch = (ks2 * 4 + qd) ^ rsw;
                    fa[ti] = *reinterpret_cast<const bf16x8*>(&Bs[row * 64 + ch * 8]);
                }
                #pragma unroll
                for (int tj = 0; tj < 2; ++tj) {
                    int row = wave * 32 + tj * 16 + l15;
                    int ch = (ks2 * 4 + qd) ^ rsw;
                    fb[tj] = *reinterpret_cast<const bf16x8*>(&As[row * 64 + ch * 8]);
                }
                #pragma unroll
                for (int ti = 0; ti < 4; ++ti)
                    #pragma unroll
                    for (int tj = 0; tj < 2; ++tj)
                        acc[ti][tj] = __builtin_amdgcn_mfma_f32_16x16x32_bf16(fa[ti], fb[tj], acc[ti][tj], 0, 0, 0);
            }
            __syncthreads();
        }

        #pragma unroll
        for (int ti = 0; ti < 4; ++ti) {
            #pragma unroll
            for (int tj = 0; tj < 2; ++tj) {
                int n = wave * 32 + tj * 16 + l15;
                #pragma unroll
                for (int r = 0; r < 4; ++r) {
                    int row = ti * 16 + qd * 4 + r;
                    int t = sperm[row];
                    if (t >= 0)
                        out[(size_t)t * CCH + n] = acc[ti][tj][r] + b_lin[k * CCH + n];
                }
            }
        }
    }
}

// ---------------------------------------------------------------------------
// Dispatch 3: LSTM pointwise epilogue (token-indexed via inverse slot map).
// ---------------------------------------------------------------------------
__global__ __launch_bounds__(256) void lstm_epilogue(
    const u16* __restrict__ gates,    // [4608][2048] bf16, slot order
    const int* __restrict__ meta,
    const int* __restrict__ inv_ci,
    const float* __restrict__ c,
    const float* __restrict__ b_ih,   // [4,2048]
    const float* __restrict__ b_hh,   // [4,2048]
    float* __restrict__ out)
{
    int idx = blockIdx.x * 256 + threadIdx.x;   // [0, N*512)
    int t = idx >> 9;
    int hh = idx & 511;
    int s = inv_ci[t];
    int m = (s >= meta[5]) + (s >= meta[6]) + (s >= meta[7]);

    const u16* g = gates + (size_t)s * G4H;
    const float* bi = b_ih + (size_t)m * G4H;
    const float* bh = b_hh + (size_t)m * G4H;
    float gi = bf2f(g[hh])        + bi[hh]        + bh[hh];
    float gf = bf2f(g[512 + hh])  + bi[512 + hh]  + bh[512 + hh];
    float gg = bf2f(g[1024 + hh]) + bi[1024 + hh] + bh[1024 + hh];
    float go = bf2f(g[1536 + hh]) + bi[1536 + hh] + bh[1536 + hh];

    float si = 1.f / (1.f + __expf(-gi));
    float sf = 1.f / (1.f + __expf(-gf));
    float so = 1.f / (1.f + __expf(-go));
    float ct = c[(size_t)t * HID + hh];
    float c2 = sf * ct + si * tanhf(gg);
    float h2 = so * tanhf(c2);

    const size_t o_h2 = (size_t)NTOK * CCH;
    const size_t o_c2 = o_h2 + (size_t)NTOK * HID;
    out[o_h2 + (size_t)t * HID + hh] = h2;
    out[o_c2 + (size_t)t * HID + hh] = c2;
}

// ---------------------------------------------------------------------------
extern "C" void kernel_launch(void* const* d_in, const int* in_sizes, int n_in,
                              void* d_out, int out_size, void* d_ws, size_t ws_size,
                              hipStream_t stream) {
    const float* et    = (const float*)d_in[0];
    const float* x     = (const float*)d_in[1];
    const float* h     = (const float*)d_in[2];
    const float* c     = (const float*)d_in[3];
    const int*   cat   = (const int*)d_in[4];
    const int*   ci    = (const int*)d_in[5];
    const float* W_lin = (const float*)d_in[6];
    const float* b_lin = (const float*)d_in[7];
    const float* W_ih  = (const float*)d_in[8];
    const float* W_hh  = (const float*)d_in[9];
    const float* b_ih  = (const float*)d_in[10];
    const float* b_hh  = (const float*)d_in[11];
    float* out = (float*)d_out;

    char* ws = (char*)d_ws;
    int* meta     = (int*)ws;                         // 136 ints
    int* perm_ci  = (int*)(ws + 1024);                // 4608 ints -> 19456
    int* perm_cat = (int*)(ws + 19456);               // 8192 ints -> 52224
    int* inv_ci   = (int*)(ws + 52224);               // 4096 ints -> 68608
    u16* A_pack   = (u16*)(ws + 68608);                           // 14155776
    u16* Wb       = (u16*)(ws + 68608 + 14155776);                // 25165824
    u16* Wlin     = (u16*)(ws + 68608 + 14155776 + 25165824);     // 8388608
    u16* et_s     = (u16*)(ws + 68608 + 14155776 + 25165824 + 8388608);  // 8388608
    u16* gates    = (u16*)(ws + 68608 + 14155776 + 25165824 + 8388608 + 8388608);
    // total ws use ~75 MB

    pack_all<<<P0_W + P0_L + 1, 192, 0, stream>>>(W_ih, W_hh, W_lin, ci, cat,
                                                  Wb, Wlin, meta, perm_ci, perm_cat);

    pack_slots<<<P1_A + P1_E, 192, 0, stream>>>(x, h, et, perm_ci, perm_cat,
                                                A_pack, et_s, inv_ci);

    dim3 ggrid(32, 16, 6);   // z<4: gates (rt,ct); z in {4,5}: logodds tiles
    mega_gemm<<<ggrid, 256, 0, stream>>>(A_pack, Wb, Wlin, et_s, b_lin, meta,
                                         perm_cat, gates, out);

    lstm_epilogue<<<(NTOK * HID) / 256, 256, 0, stream>>>(gates, meta, inv_ci, c,
                                                          b_ih, b_hh, out);
}